// Round 10
// baseline (1049.680 us; speedup 1.0000x reference)
//
#include <hip/hip_runtime.h>
#include <hip/hip_bf16.h>
#include <hip/hip_cooperative_groups.h>

#define N_NODES 50000
#define N_EDGES 600000
#define N_GRAPHS 64
#define HID 128
#define NLAYERS 4
#define IN_DIM 5
#define NCLS 5
#define EPS 1e-5f
#define SCAN_BLK ((N_NODES + 511) / 512)
#define FILL_BLK ((N_EDGES + 255) / 256)
#define POOL_CHUNKS 16
#define BSLOT 64   // BN-stat atomic slots (per layer)
#define WS2 136    // bf16 LDS row stride for Al (16B-aligned rows)

typedef __attribute__((ext_vector_type(8))) short s16x8;
typedef __attribute__((ext_vector_type(4))) float f32x4;

// bf16 helpers (RNE)
__device__ __forceinline__ unsigned short f2bf(float x) {
    unsigned u = __float_as_uint(x);
    unsigned r = (u + 0x7fffu + ((u >> 16) & 1u)) >> 16;
    return (unsigned short)r;
}
__device__ __forceinline__ float2 bfpair(unsigned u) {
    float2 r;
    r.x = __uint_as_float(u << 16);
    r.y = __uint_as_float(u & 0xffff0000u);
    return r;
}
__device__ __forceinline__ float bf2f(unsigned short s) {
    return __uint_as_float(((unsigned)s) << 16);
}

// ---------------- CSR build ----------------

__global__ void k_count(const int* __restrict__ dst, int* __restrict__ cnt) {
    int i = blockIdx.x * blockDim.x + threadIdx.x;
    if (i < N_EDGES) atomicAdd(&cnt[dst[i]], 1);
}

__global__ void k_scan1(const int* __restrict__ cnt, int* __restrict__ rp, int* __restrict__ bsum) {
    __shared__ int s[512];
    int t = threadIdx.x;
    int i = blockIdx.x * 512 + t;
    int v = (i < N_NODES) ? cnt[i] : 0;
    s[t] = v;
    __syncthreads();
    for (int off = 1; off < 512; off <<= 1) {
        int x = (t >= off) ? s[t - off] : 0;
        __syncthreads();
        s[t] += x;
        __syncthreads();
    }
    if (i < N_NODES) rp[i + 1] = s[t];
    if (t == 511) bsum[blockIdx.x] = s[511];
}

__global__ void k_scan2g(int* __restrict__ bsum, const int* __restrict__ batch,
                         int* __restrict__ gstart) {
    if (blockIdx.x == 0) {
        __shared__ int s[128];
        int t = threadIdx.x;
        int v = (t < SCAN_BLK) ? bsum[t] : 0;
        s[t] = v;
        __syncthreads();
        for (int off = 1; off < 128; off <<= 1) {
            int x = (t >= off) ? s[t - off] : 0;
            __syncthreads();
            s[t] += x;
            __syncthreads();
        }
        if (t < SCAN_BLK) bsum[t] = s[t] - v;
    } else {
        int t = threadIdx.x;
        if (t <= N_GRAPHS) {
            int lo = 0, hi = N_NODES;
            while (lo < hi) {
                int mid = (lo + hi) >> 1;
                if (batch[mid] < t) lo = mid + 1; else hi = mid;
            }
            gstart[t] = lo;
        }
    }
}

__global__ void k_scan3d(int* __restrict__ rp, const int* __restrict__ bsum,
                         const int* __restrict__ cnt, float* __restrict__ dinv) {
    int i = blockIdx.x * 512 + threadIdx.x;
    if (i < N_NODES) {
        rp[i + 1] += bsum[blockIdx.x];
        dinv[i] = rsqrtf((float)(cnt[i] + 1));
    }
    if (i == 0) rp[0] = 0;
}

// fill packed (col, w) pairs; trailing blocks do the W transpose+bf16 convert
__global__ void k_fillw(const int* __restrict__ src, const int* __restrict__ dst,
                        const int* __restrict__ rp, int* __restrict__ cursor,
                        int2* __restrict__ cw, const float* __restrict__ dinv,
                        const float* __restrict__ Wg, unsigned short* __restrict__ WtG) {
    int b = blockIdx.x;
    if (b < FILL_BLK) {
        int e = b * 256 + threadIdx.x;
        if (e < N_EDGES) {
            int d = dst[e];
            int pos = atomicAdd(&cursor[d], 1);
            int s = src[e];
            int2 p;
            p.x = s;
            p.y = __float_as_int(dinv[s]);
            cw[rp[d] + pos] = p;
        }
    } else {
        int idx = (b - FILL_BLK) * 256 + threadIdx.x;  // < NLAYERS*HID*HID
        int l = idx >> 14;
        int r = idx & 16383;
        int n = r >> 7, k = r & 127;
        WtG[idx] = f2bf(Wg[l * HID * HID + k * HID + n]);
    }
}

// ---------------- the cooperative mega-kernel ----------------
// Phases (grid-stride, grid.sync between):
//   for layer 0..3: GEMM (MFMA, B-frags direct from global WtG) ; sync ;
//                   gather (+BN partial stats) ; sync
//   pool ; sync ; head.

struct GemmSM {
    unsigned short Al[64 * WS2];           // 17408 B
    union {
        struct { float scl[HID]; float shf[HID]; } bn;          // 1024 B
        struct { float Wpl[IN_DIM * HID]; float bpl[HID]; } p0; // 3072 B
    } u;
};
struct RedSM { float ls[4 * HID]; float lq[4 * HID]; };
struct HeadSM { float pl[2 * HID]; float h1[HID]; float h2[HID / 2]; };
union SMem { GemmSM g; RedSM r; HeadSM h; };  // 20480 B

__global__ __launch_bounds__(256) void k_mega(
    const float* __restrict__ x,
    const float* __restrict__ Wp, const float* __restrict__ bp,
    const unsigned short* __restrict__ WtG,
    const float* __restrict__ bg,
    const float* __restrict__ gamma, const float* __restrict__ beta,
    const int* __restrict__ rp, const int2* __restrict__ cw,
    const float* __restrict__ dinv, const int* __restrict__ gstart,
    const float* __restrict__ W1, const float* __restrict__ b1,
    const float* __restrict__ W2, const float* __restrict__ b2,
    const float* __restrict__ W3, const float* __restrict__ b3,
    unsigned short* __restrict__ A, unsigned short* __restrict__ B,
    float* __restrict__ psum, float* __restrict__ psq,
    float* __restrict__ poolPart, float* __restrict__ out)
{
    __shared__ SMem sm;
    cooperative_groups::grid_group grid = cooperative_groups::this_grid();
    int t = threadIdx.x;
    int lane = t & 63, wv = t >> 6;
    int rbase = (wv & 1) * 32;
    int cbase = (wv >> 1) * 64;
    int mr = lane & 15, q = lane >> 4;
    const int numTiles = (N_NODES + 63) / 64;

    for (int layer = 0; layer < NLAYERS; layer++) {
        // ---- GEMM phase ----
        const unsigned short* WtL = WtG + (size_t)layer * HID * HID;
        if (layer == 0) {
            for (int idx = t; idx < IN_DIM * HID; idx += 256) sm.g.u.p0.Wpl[idx] = Wp[idx];
            if (t < HID) sm.g.u.p0.bpl[t] = bp[t];
        } else if (t < HID) {
            const float* ps = psum + (size_t)(layer - 1) * BSLOT * HID;
            const float* pq = psq + (size_t)(layer - 1) * BSLOT * HID;
            float s = 0.f, s2 = 0.f;
#pragma unroll 8
            for (int b = 0; b < BSLOT; b++) {
                s += ps[b * HID + t];
                s2 += pq[b * HID + t];
            }
            const float invN = 1.f / (float)N_NODES;
            float mu = s * invN;
            float var = s2 * invN - mu * mu;
            float rs = rsqrtf(var + EPS) * gamma[(layer - 1) * HID + t];
            sm.g.u.bn.scl[t] = rs;
            sm.g.u.bn.shf[t] = beta[(layer - 1) * HID + t] - mu * rs;
        }
        for (int tile = blockIdx.x; tile < numTiles; tile += gridDim.x) {
            int n0 = tile * 64;
            __syncthreads();  // orders scl/Wpl writes + Al reuse
            if (layer == 0) {
                for (int idx = t; idx < 64 * HID; idx += 256) {
                    int n = idx >> 7, k = idx & 127;
                    int node = n0 + n;
                    float acc = sm.g.u.p0.bpl[k];
                    if (node < N_NODES) {
#pragma unroll
                        for (int j = 0; j < IN_DIM; j++)
                            acc += x[node * IN_DIM + j] * sm.g.u.p0.Wpl[j * HID + k];
                    }
                    sm.g.Al[n * WS2 + k] = f2bf(acc);
                }
            } else {
                const uint2* Ag = (const uint2*)(A + (size_t)n0 * HID);
                int limRow = min(64, N_NODES - n0);
                for (int idx = t; idx < 64 * 32; idx += 256) {
                    int row = idx >> 5, c4 = idx & 31;
                    uint2 u = (row < limRow) ? Ag[row * 32 + c4] : make_uint2(0u, 0u);
                    float2 ab = bfpair(u.x);
                    float2 cd = bfpair(u.y);
                    int kf = c4 * 4;
                    float4 sc = *(const float4*)&sm.g.u.bn.scl[kf];
                    float4 sh = *(const float4*)&sm.g.u.bn.shf[kf];
                    float v0 = fmaxf(ab.x * sc.x + sh.x, 0.f);
                    float v1 = fmaxf(ab.y * sc.y + sh.y, 0.f);
                    float v2 = fmaxf(cd.x * sc.z + sh.z, 0.f);
                    float v3 = fmaxf(cd.y * sc.w + sh.w, 0.f);
                    unsigned lo = (unsigned)f2bf(v0) | ((unsigned)f2bf(v1) << 16);
                    unsigned hi = (unsigned)f2bf(v2) | ((unsigned)f2bf(v3) << 16);
                    *(uint2*)&sm.g.Al[row * WS2 + kf] = make_uint2(lo, hi);
                }
            }
            __syncthreads();
            f32x4 acc[2][4];
#pragma unroll
            for (int rt = 0; rt < 2; rt++)
#pragma unroll
                for (int ct = 0; ct < 4; ct++) acc[rt][ct] = (f32x4){0.f, 0.f, 0.f, 0.f};
#pragma unroll
            for (int kk = 0; kk < HID; kk += 32) {
                s16x8 a0 = *(const s16x8*)&sm.g.Al[(rbase + mr) * WS2 + kk + q * 8];
                s16x8 a1 = *(const s16x8*)&sm.g.Al[(rbase + 16 + mr) * WS2 + kk + q * 8];
#pragma unroll
                for (int ct = 0; ct < 4; ct++) {
                    s16x8 b = *(const s16x8*)&WtL[(cbase + ct * 16 + mr) * HID + kk + q * 8];
                    acc[0][ct] = __builtin_amdgcn_mfma_f32_16x16x32_bf16(a0, b, acc[0][ct], 0, 0, 0);
                    acc[1][ct] = __builtin_amdgcn_mfma_f32_16x16x32_bf16(a1, b, acc[1][ct], 0, 0, 0);
                }
            }
#pragma unroll
            for (int rt = 0; rt < 2; rt++)
#pragma unroll
                for (int ct = 0; ct < 4; ct++)
#pragma unroll
                    for (int r = 0; r < 4; r++) {
                        int node = n0 + rbase + rt * 16 + q * 4 + r;
                        if (node < N_NODES) {
                            int f = cbase + ct * 16 + mr;
                            B[(size_t)node * HID + f] = f2bf(acc[rt][ct][r]);
                        }
                    }
        }
        grid.sync();

        // ---- gather phase ----
        {
            const uint4* Bm4 = (const uint4*)B;
            const float* bgL = bg + layer * HID;
            float* psL = psum + (size_t)layer * BSLOT * HID;
            float* pqL = psq + (size_t)layer * BSLOT * HID;
            int s = lane & 15;   // 16B feature chunk
            int p = lane >> 4;   // edge slot 0..3
            int f = s * 8;
            for (int grp = blockIdx.x; grp < N_NODES / 16; grp += gridDim.x) {
                float ts0 = 0.f, ts1 = 0.f, ts2 = 0.f, ts3 = 0.f;
                float ts4 = 0.f, ts5 = 0.f, ts6 = 0.f, ts7 = 0.f;
                float tq0 = 0.f, tq1 = 0.f, tq2 = 0.f, tq3 = 0.f;
                float tq4 = 0.f, tq5 = 0.f, tq6 = 0.f, tq7 = 0.f;
#pragma unroll 1
                for (int it = 0; it < 4; it++) {
                    int v = grp * 16 + wv * 4 + it;
                    int beg = rp[v], end = rp[v + 1];
                    float dv = dinv[v];
                    float a0 = 0.f, a1 = 0.f, a2 = 0.f, a3 = 0.f;
                    float a4 = 0.f, a5 = 0.f, a6 = 0.f, a7 = 0.f;
                    if (p == 0) {  // self-loop term
                        uint4 u = Bm4[(size_t)v * 16 + s];
                        float2 q0 = bfpair(u.x), q1 = bfpair(u.y), q2 = bfpair(u.z), q3 = bfpair(u.w);
                        a0 = q0.x * dv; a1 = q0.y * dv; a2 = q1.x * dv; a3 = q1.y * dv;
                        a4 = q2.x * dv; a5 = q2.y * dv; a6 = q3.x * dv; a7 = q3.y * dv;
                    }
                    int e = beg + p;
                    for (; e + 4 < end; e += 8) {
                        int2 pe0 = cw[e];
                        int2 pe1 = cw[e + 4];
                        uint4 u0 = Bm4[(size_t)pe0.x * 16 + s];
                        uint4 u1 = Bm4[(size_t)pe1.x * 16 + s];
                        float w0 = __int_as_float(pe0.y);
                        float w1 = __int_as_float(pe1.y);
                        float2 x0 = bfpair(u0.x), x1 = bfpair(u0.y), x2 = bfpair(u0.z), x3 = bfpair(u0.w);
                        float2 y0 = bfpair(u1.x), y1 = bfpair(u1.y), y2 = bfpair(u1.z), y3 = bfpair(u1.w);
                        a0 += x0.x * w0 + y0.x * w1;
                        a1 += x0.y * w0 + y0.y * w1;
                        a2 += x1.x * w0 + y1.x * w1;
                        a3 += x1.y * w0 + y1.y * w1;
                        a4 += x2.x * w0 + y2.x * w1;
                        a5 += x2.y * w0 + y2.y * w1;
                        a6 += x3.x * w0 + y3.x * w1;
                        a7 += x3.y * w0 + y3.y * w1;
                    }
                    if (e < end) {
                        int2 pe = cw[e];
                        uint4 u = Bm4[(size_t)pe.x * 16 + s];
                        float w = __int_as_float(pe.y);
                        float2 x0 = bfpair(u.x), x1 = bfpair(u.y), x2 = bfpair(u.z), x3 = bfpair(u.w);
                        a0 += x0.x * w; a1 += x0.y * w; a2 += x1.x * w; a3 += x1.y * w;
                        a4 += x2.x * w; a5 += x2.y * w; a6 += x3.x * w; a7 += x3.y * w;
                    }
                    a0 += __shfl_xor(a0, 16); a1 += __shfl_xor(a1, 16);
                    a2 += __shfl_xor(a2, 16); a3 += __shfl_xor(a3, 16);
                    a4 += __shfl_xor(a4, 16); a5 += __shfl_xor(a5, 16);
                    a6 += __shfl_xor(a6, 16); a7 += __shfl_xor(a7, 16);
                    a0 += __shfl_xor(a0, 32); a1 += __shfl_xor(a1, 32);
                    a2 += __shfl_xor(a2, 32); a3 += __shfl_xor(a3, 32);
                    a4 += __shfl_xor(a4, 32); a5 += __shfl_xor(a5, 32);
                    a6 += __shfl_xor(a6, 32); a7 += __shfl_xor(a7, 32);
                    if (p == 0) {
                        float r0 = a0 * dv + bgL[f + 0];
                        float r1 = a1 * dv + bgL[f + 1];
                        float r2 = a2 * dv + bgL[f + 2];
                        float r3 = a3 * dv + bgL[f + 3];
                        float r4 = a4 * dv + bgL[f + 4];
                        float r5 = a5 * dv + bgL[f + 5];
                        float r6 = a6 * dv + bgL[f + 6];
                        float r7 = a7 * dv + bgL[f + 7];
                        unsigned short b0 = f2bf(r0), b1 = f2bf(r1), b2 = f2bf(r2), b3 = f2bf(r3);
                        unsigned short b4 = f2bf(r4), b5 = f2bf(r5), b6 = f2bf(r6), b7 = f2bf(r7);
                        uint4 o;
                        o.x = (unsigned)b0 | ((unsigned)b1 << 16);
                        o.y = (unsigned)b2 | ((unsigned)b3 << 16);
                        o.z = (unsigned)b4 | ((unsigned)b5 << 16);
                        o.w = (unsigned)b6 | ((unsigned)b7 << 16);
                        *(uint4*)&A[(size_t)v * HID + f] = o;
                        float v0 = bf2f(b0), v1 = bf2f(b1), v2 = bf2f(b2), v3 = bf2f(b3);
                        float v4 = bf2f(b4), v5 = bf2f(b5), v6 = bf2f(b6), v7 = bf2f(b7);
                        ts0 += v0; ts1 += v1; ts2 += v2; ts3 += v3;
                        ts4 += v4; ts5 += v5; ts6 += v6; ts7 += v7;
                        tq0 += v0 * v0; tq1 += v1 * v1; tq2 += v2 * v2; tq3 += v3 * v3;
                        tq4 += v4 * v4; tq5 += v5 * v5; tq6 += v6 * v6; tq7 += v7 * v7;
                    }
                }
                if (p == 0) {
                    float* lsw = &sm.r.ls[wv * HID + f];
                    float* lqw = &sm.r.lq[wv * HID + f];
                    lsw[0] = ts0; lsw[1] = ts1; lsw[2] = ts2; lsw[3] = ts3;
                    lsw[4] = ts4; lsw[5] = ts5; lsw[6] = ts6; lsw[7] = ts7;
                    lqw[0] = tq0; lqw[1] = tq1; lqw[2] = tq2; lqw[3] = tq3;
                    lqw[4] = tq4; lqw[5] = tq5; lqw[6] = tq6; lqw[7] = tq7;
                }
                __syncthreads();
                if (t < HID) {
                    float ssum = sm.r.ls[t] + sm.r.ls[HID + t] + sm.r.ls[2 * HID + t] + sm.r.ls[3 * HID + t];
                    float ssq = sm.r.lq[t] + sm.r.lq[HID + t] + sm.r.lq[2 * HID + t] + sm.r.lq[3 * HID + t];
                    int slot = grp & (BSLOT - 1);
                    atomicAdd(&psL[slot * HID + t], ssum);
                    atomicAdd(&pqL[slot * HID + t], ssq);
                }
                __syncthreads();  // LDS reuse across grp iterations
            }
        }
        grid.sync();
    }

    // ---- pool phase ----
    {
        int f = t & 127;
        int half = t >> 7;
        if (blockIdx.x * 2 < N_GRAPHS * POOL_CHUNKS) {
            const float* ps = psum + (size_t)(NLAYERS - 1) * BSLOT * HID;
            const float* pq = psq + (size_t)(NLAYERS - 1) * BSLOT * HID;
            float s = 0.f, s2 = 0.f;
#pragma unroll 8
            for (int b = 0; b < BSLOT; b++) {
                s += ps[b * HID + f];
                s2 += pq[b * HID + f];
            }
            const float invN = 1.f / (float)N_NODES;
            float mu = s * invN;
            float var = s2 * invN - mu * mu;
            float sc = rsqrtf(var + EPS) * gamma[(NLAYERS - 1) * HID + f];
            float sh = beta[(NLAYERS - 1) * HID + f] - mu * sc;
            for (int item = blockIdx.x * 2 + half; item < N_GRAPHS * POOL_CHUNKS; item += gridDim.x * 2) {
                int g = item >> 4, c = item & 15;
                int beg = gstart[g], end = gstart[g + 1];
                int len = end - beg;
                int per = (len + POOL_CHUNKS - 1) / POOL_CHUNKS;
                int s0 = beg + c * per;
                int s1 = min(s0 + per, end);
                float sa = 0.f, sb = 0.f, ma = 0.f, mb = 0.f;
                int n = s0;
                for (; n + 1 < s1; n += 2) {
                    float v0 = bf2f(A[(size_t)n * HID + f]);
                    float v1 = bf2f(A[(size_t)(n + 1) * HID + f]);
                    v0 = fmaxf(v0 * sc + sh, 0.f);
                    v1 = fmaxf(v1 * sc + sh, 0.f);
                    sa += v0; ma = fmaxf(ma, v0);
                    sb += v1; mb = fmaxf(mb, v1);
                }
                if (n < s1) {
                    float v = fmaxf(bf2f(A[(size_t)n * HID + f]) * sc + sh, 0.f);
                    sa += v; ma = fmaxf(ma, v);
                }
                poolPart[(size_t)item * 256 + f] = sa + sb;
                poolPart[(size_t)item * 256 + 128 + f] = fmaxf(ma, mb);
            }
        }
    }
    grid.sync();

    // ---- head phase ----
    if (blockIdx.x < N_GRAPHS) {
        int g = blockIdx.x;
        if (t < HID) {
            float cnt = fmaxf((float)(gstart[g + 1] - gstart[g]), 1.f);
            float s = 0.f, mx = 0.f;
#pragma unroll
            for (int c = 0; c < POOL_CHUNKS; c++) {
                const float* p = &poolPart[(size_t)(g * POOL_CHUNKS + c) * 256];
                s += p[t];
                mx = fmaxf(mx, p[128 + t]);
            }
            sm.h.pl[t] = s / cnt;
            sm.h.pl[HID + t] = mx;
        }
        __syncthreads();
        if (t < HID) {
            float acc = b1[t];
            for (int k = 0; k < 2 * HID; k++) acc += sm.h.pl[k] * W1[k * HID + t];
            sm.h.h1[t] = fmaxf(acc, 0.f);
        }
        __syncthreads();
        if (t < HID / 2) {
            float a2 = b2[t];
            for (int k = 0; k < HID; k++) a2 += sm.h.h1[k] * W2[k * (HID / 2) + t];
            sm.h.h2[t] = fmaxf(a2, 0.f);
        }
        __syncthreads();
        if (t < NCLS) {
            float a3 = b3[t];
            for (int k = 0; k < HID / 2; k++) a3 += sm.h.h2[k] * W3[k * NCLS + t];
            out[g * NCLS + t] = a3;
        }
    }
}

extern "C" void kernel_launch(void* const* d_in, const int* in_sizes, int n_in,
                              void* d_out, int out_size, void* d_ws, size_t ws_size,
                              hipStream_t stream) {
    const float* x     = (const float*)d_in[0];
    const int*   ei    = (const int*)d_in[1];
    const int*   batch = (const int*)d_in[2];
    const float* Wp    = (const float*)d_in[3];
    const float* bp    = (const float*)d_in[4];
    const float* Wg    = (const float*)d_in[5];
    const float* bg    = (const float*)d_in[6];
    const float* gamma = (const float*)d_in[7];
    const float* beta  = (const float*)d_in[8];
    const float* W1    = (const float*)d_in[9];
    const float* b1    = (const float*)d_in[10];
    const float* W2    = (const float*)d_in[11];
    const float* b2    = (const float*)d_in[12];
    const float* W3    = (const float*)d_in[13];
    const float* b3    = (const float*)d_in[14];
    const int* src = ei;
    const int* dst = ei + N_EDGES;
    float* out = (float*)d_out;

    char* base = (char*)d_ws;
    size_t off = 0;
    auto alloc = [&](size_t bytes) -> void* {
        void* p = base + off;
        off += (bytes + 255) & ~(size_t)255;
        return p;
    };
    // zeroed region (one memset)
    int*   counts = (int*)alloc((size_t)N_NODES * 4);
    int*   cursor = (int*)alloc((size_t)N_NODES * 4);
    float* psum   = (float*)alloc((size_t)NLAYERS * BSLOT * HID * 4);
    float* psq    = (float*)alloc((size_t)NLAYERS * BSLOT * HID * 4);
    size_t zeroBytes = off;
    // non-zeroed scratch
    int*   rp      = (int*)alloc((size_t)(N_NODES + 1) * 4);
    int*   bsum    = (int*)alloc(128 * 4);
    int2*  cw      = (int2*)alloc((size_t)N_EDGES * 8);
    float* dinv    = (float*)alloc((size_t)N_NODES * 4);
    int*   gstart  = (int*)alloc((size_t)(N_GRAPHS + 1) * 4);
    float* poolPart= (float*)alloc((size_t)N_GRAPHS * POOL_CHUNKS * 256 * 4);
    unsigned short* WtG = (unsigned short*)alloc((size_t)NLAYERS * HID * HID * 2);
    unsigned short* A = (unsigned short*)alloc((size_t)N_NODES * HID * 2);
    unsigned short* B = (unsigned short*)alloc((size_t)N_NODES * HID * 2);
    (void)ws_size; (void)in_sizes; (void)n_in; (void)out_size;

    hipMemsetAsync(d_ws, 0, zeroBytes, stream);

    k_count<<<(N_EDGES + 255) / 256, 256, 0, stream>>>(dst, counts);
    k_scan1<<<SCAN_BLK, 512, 0, stream>>>(counts, rp, bsum);
    k_scan2g<<<2, 128, 0, stream>>>(bsum, batch, gstart);
    k_scan3d<<<SCAN_BLK, 512, 0, stream>>>(rp, bsum, counts, dinv);
    k_fillw<<<FILL_BLK + (NLAYERS * HID * HID) / 256, 256, 0, stream>>>(
        src, dst, rp, cursor, cw, dinv, Wg, WtG);

    int nb = 0;
    if (hipOccupancyMaxActiveBlocksPerMultiprocessor(&nb, k_mega, 256, 0) != hipSuccess || nb < 1)
        nb = 2;
    int gridSz = nb * 256;  // 256 CUs on MI355X
    void* args[] = {(void*)&x, (void*)&Wp, (void*)&bp, (void*)&WtG, (void*)&bg,
                    (void*)&gamma, (void*)&beta, (void*)&rp, (void*)&cw, (void*)&dinv,
                    (void*)&gstart, (void*)&W1, (void*)&b1, (void*)&W2, (void*)&b2,
                    (void*)&W3, (void*)&b3, (void*)&A, (void*)&B, (void*)&psum,
                    (void*)&psq, (void*)&poolPart, (void*)&out};
    hipLaunchCooperativeKernel((void*)k_mega, dim3(gridSz), dim3(256), args, 0, stream);
}

// Round 11
// 422.614 us; speedup vs baseline: 2.4838x; 2.4838x over previous
//
#include <hip/hip_runtime.h>
#include <hip/hip_bf16.h>

#define N_NODES 50000
#define N_EDGES 600000
#define N_GRAPHS 64
#define HID 128
#define NLAYERS 4
#define IN_DIM 5
#define NCLS 5
#define EPS 1e-5f
#define SCAN_BLK ((N_NODES + 511) / 512)
#define FILL_BLK ((N_EDGES + 255) / 256)
#define POOL_CHUNKS 16
#define BSLOT 64  // BN-stat atomic slots (per layer)
#define WS 136    // bf16 LDS row stride (MFMA kernel)

typedef __attribute__((ext_vector_type(8))) short s16x8;
typedef __attribute__((ext_vector_type(4))) float f32x4;

// bf16 helpers (RNE)
__device__ __forceinline__ unsigned short f2bf(float x) {
    unsigned u = __float_as_uint(x);
    unsigned r = (u + 0x7fffu + ((u >> 16) & 1u)) >> 16;
    return (unsigned short)r;
}
__device__ __forceinline__ float2 bfpair(unsigned u) {
    float2 r;
    r.x = __uint_as_float(u << 16);
    r.y = __uint_as_float(u & 0xffff0000u);
    return r;
}
__device__ __forceinline__ float bf2f(unsigned short s) {
    return __uint_as_float(((unsigned)s) << 16);
}

// ---------------- CSR build ----------------

__global__ void k_count(const int* __restrict__ dst, int* __restrict__ cnt) {
    int i = blockIdx.x * blockDim.x + threadIdx.x;
    if (i < N_EDGES) atomicAdd(&cnt[dst[i]], 1);
}

__global__ void k_scan1(const int* __restrict__ cnt, int* __restrict__ rp, int* __restrict__ bsum) {
    __shared__ int s[512];
    int t = threadIdx.x;
    int i = blockIdx.x * 512 + t;
    int v = (i < N_NODES) ? cnt[i] : 0;
    s[t] = v;
    __syncthreads();
    for (int off = 1; off < 512; off <<= 1) {
        int x = (t >= off) ? s[t - off] : 0;
        __syncthreads();
        s[t] += x;
        __syncthreads();
    }
    if (i < N_NODES) rp[i + 1] = s[t];
    if (t == 511) bsum[blockIdx.x] = s[511];
}

__global__ void k_scan2g(int* __restrict__ bsum, const int* __restrict__ batch,
                         int* __restrict__ gstart) {
    if (blockIdx.x == 0) {
        __shared__ int s[128];
        int t = threadIdx.x;
        int v = (t < SCAN_BLK) ? bsum[t] : 0;
        s[t] = v;
        __syncthreads();
        for (int off = 1; off < 128; off <<= 1) {
            int x = (t >= off) ? s[t - off] : 0;
            __syncthreads();
            s[t] += x;
            __syncthreads();
        }
        if (t < SCAN_BLK) bsum[t] = s[t] - v;
    } else {
        int t = threadIdx.x;
        if (t <= N_GRAPHS) {
            int lo = 0, hi = N_NODES;
            while (lo < hi) {
                int mid = (lo + hi) >> 1;
                if (batch[mid] < t) lo = mid + 1; else hi = mid;
            }
            gstart[t] = lo;
        }
    }
}

__global__ void k_scan3d(int* __restrict__ rp, const int* __restrict__ bsum,
                         const int* __restrict__ cnt, float* __restrict__ dinv) {
    int i = blockIdx.x * 512 + threadIdx.x;
    if (i < N_NODES) {
        rp[i + 1] += bsum[blockIdx.x];
        dinv[i] = rsqrtf((float)(cnt[i] + 1));
    }
    if (i == 0) rp[0] = 0;
}

// fill packed (col, w) pairs; trailing blocks do the W transpose+bf16 convert
__global__ void k_fillw(const int* __restrict__ src, const int* __restrict__ dst,
                        const int* __restrict__ rp, int* __restrict__ cursor,
                        int2* __restrict__ cw, const float* __restrict__ dinv,
                        const float* __restrict__ Wg, unsigned short* __restrict__ WtG) {
    int b = blockIdx.x;
    if (b < FILL_BLK) {
        int e = b * 256 + threadIdx.x;
        if (e < N_EDGES) {
            int d = dst[e];
            int pos = atomicAdd(&cursor[d], 1);
            int s = src[e];
            int2 p;
            p.x = s;
            p.y = __float_as_int(dinv[s]);
            cw[rp[d] + pos] = p;
        }
    } else {
        int idx = (b - FILL_BLK) * 256 + threadIdx.x;  // < NLAYERS*HID*HID
        int l = idx >> 14;
        int r = idx & 16383;
        int n = r >> 7, k = r & 127;
        WtG[idx] = f2bf(Wg[l * HID * HID + k * HID + n]);
    }
}

// ---------------- GEMM (MFMA): Bm(bf16) = act(in) @ W ----------------
// layer0: in = x @ Wp + bp (computed per tile). Else: in = relu(A*sc+sh),
// sc/sh derived in-kernel from the previous gather's psum/psq slots.
// W comes pre-transposed+bf16 (WtG[n][k]) -> coalesced uint4 + ds_write_b128.

__global__ __launch_bounds__(256) void k_gemmM(const unsigned short* __restrict__ Abf,
                                               const float* __restrict__ x,
                                               const float* __restrict__ Wp,
                                               const float* __restrict__ bp,
                                               const unsigned short* __restrict__ WtG,
                                               unsigned short* __restrict__ Bm,
                                               const float* __restrict__ psum,
                                               const float* __restrict__ psq,
                                               const float* __restrict__ gamma,
                                               const float* __restrict__ beta,
                                               int layer0) {
    __shared__ unsigned short Wt[HID * WS];
    __shared__ unsigned short Al[64 * WS];
    __shared__ float scl[HID], shf[HID];
    __shared__ float Wpl[IN_DIM * HID];
    __shared__ float bpl[HID];
    __shared__ float xl[64 * IN_DIM];
    int t = threadIdx.x;
    {
        const uint4* Wg4 = (const uint4*)WtG;
        for (int idx = t; idx < HID * 16; idx += 256) {
            int n = idx >> 4, c = idx & 15;
            *(uint4*)&Wt[n * WS + c * 8] = Wg4[idx];
        }
    }
    if (layer0) {
        for (int idx = t; idx < IN_DIM * HID; idx += 256) Wpl[idx] = Wp[idx];
        if (t < HID) bpl[t] = bp[t];
    } else if (t < HID) {
        float s = 0.f, s2 = 0.f;
#pragma unroll 8
        for (int b = 0; b < BSLOT; b++) {
            s += psum[b * HID + t];
            s2 += psq[b * HID + t];
        }
        const float invN = 1.f / (float)N_NODES;
        float mu = s * invN;
        float var = s2 * invN - mu * mu;
        float rs = rsqrtf(var + EPS) * gamma[t];
        scl[t] = rs;
        shf[t] = beta[t] - mu * rs;
    }
    int lane = t & 63, wv = t >> 6;
    int rbase = (wv & 1) * 32;
    int cbase = (wv >> 1) * 64;
    int mr = lane & 15, q = lane >> 4;
    const int numTiles = (N_NODES + 63) / 64;
    for (int tile = blockIdx.x; tile < numTiles; tile += gridDim.x) {
        int n0 = tile * 64;
        __syncthreads();  // orders scl/Wt writes (1st iter) + Al reuse safety
        if (layer0) {
            for (int idx = t; idx < 64 * IN_DIM; idx += 256) {
                int g = n0 * IN_DIM + idx;
                xl[idx] = (g < N_NODES * IN_DIM) ? x[g] : 0.f;
            }
            __syncthreads();
            for (int idx = t; idx < 64 * HID; idx += 256) {
                int n = idx >> 7, k = idx & 127;
                float acc = bpl[k];
#pragma unroll
                for (int j = 0; j < IN_DIM; j++) acc += xl[n * IN_DIM + j] * Wpl[j * HID + k];
                Al[n * WS + k] = f2bf(acc);
            }
        } else {
            const uint2* Ag = (const uint2*)(Abf + (size_t)n0 * HID);
            int limRow = min(64, N_NODES - n0);
            for (int idx = t; idx < 64 * 32; idx += 256) {
                int row = idx >> 5, c4 = idx & 31;
                uint2 u = (row < limRow) ? Ag[row * 32 + c4] : make_uint2(0u, 0u);
                float2 ab = bfpair(u.x);
                float2 cd = bfpair(u.y);
                int kf = c4 * 4;
                float4 sc = *(const float4*)&scl[kf];
                float4 sh = *(const float4*)&shf[kf];
                float v0 = fmaxf(ab.x * sc.x + sh.x, 0.f);
                float v1 = fmaxf(ab.y * sc.y + sh.y, 0.f);
                float v2 = fmaxf(cd.x * sc.z + sh.z, 0.f);
                float v3 = fmaxf(cd.y * sc.w + sh.w, 0.f);
                unsigned lo = (unsigned)f2bf(v0) | ((unsigned)f2bf(v1) << 16);
                unsigned hi = (unsigned)f2bf(v2) | ((unsigned)f2bf(v3) << 16);
                *(uint2*)&Al[row * WS + kf] = make_uint2(lo, hi);
            }
        }
        __syncthreads();
        f32x4 acc[2][4];
#pragma unroll
        for (int rt = 0; rt < 2; rt++)
#pragma unroll
            for (int ct = 0; ct < 4; ct++) acc[rt][ct] = (f32x4){0.f, 0.f, 0.f, 0.f};
#pragma unroll
        for (int kk = 0; kk < HID; kk += 32) {
            s16x8 a0 = *(const s16x8*)&Al[(rbase + mr) * WS + kk + q * 8];
            s16x8 a1 = *(const s16x8*)&Al[(rbase + 16 + mr) * WS + kk + q * 8];
#pragma unroll
            for (int ct = 0; ct < 4; ct++) {
                s16x8 b = *(const s16x8*)&Wt[(cbase + ct * 16 + mr) * WS + kk + q * 8];
                acc[0][ct] = __builtin_amdgcn_mfma_f32_16x16x32_bf16(a0, b, acc[0][ct], 0, 0, 0);
                acc[1][ct] = __builtin_amdgcn_mfma_f32_16x16x32_bf16(a1, b, acc[1][ct], 0, 0, 0);
            }
        }
#pragma unroll
        for (int rt = 0; rt < 2; rt++)
#pragma unroll
            for (int ct = 0; ct < 4; ct++)
#pragma unroll
                for (int r = 0; r < 4; r++) {
                    int node = n0 + rbase + rt * 16 + q * 4 + r;
                    if (node < N_NODES) {
                        int f = cbase + ct * 16 + mr;
                        Bm[(size_t)node * HID + f] = f2bf(acc[rt][ct][r]);
                    }
                }
    }
}

// ---------------- CSR gather + fused BN partial stats ----------------
// 16 nodes per block: 4 waves x 4 serial nodes. Within a node, four 16-lane
// groups each fetch a DIFFERENT edge's 256B row (uint4/lane), unroll x4 ->
// 16 rows in flight per wave. BN stats accumulate in registers across the
// 4 nodes; one LDS reduce + 256-atomic tail per block.

__global__ __launch_bounds__(256) void k_gather(const uint4* __restrict__ Bm4,
                                                const int* __restrict__ rp,
                                                const int2* __restrict__ cw,
                                                const float* __restrict__ dinv,
                                                const float* __restrict__ bg,
                                                unsigned short* __restrict__ Aout,
                                                float* __restrict__ psum,
                                                float* __restrict__ psq) {
    __shared__ float ls[4 * HID], lq[4 * HID];
    int wave = threadIdx.x >> 6;
    int lane = threadIdx.x & 63;
    int s = lane & 15;   // 16B feature chunk: features s*8 .. s*8+7
    int p = lane >> 4;   // edge slot 0..3
    int f = s * 8;
    float ts0 = 0.f, ts1 = 0.f, ts2 = 0.f, ts3 = 0.f, ts4 = 0.f, ts5 = 0.f, ts6 = 0.f, ts7 = 0.f;
    float tq0 = 0.f, tq1 = 0.f, tq2 = 0.f, tq3 = 0.f, tq4 = 0.f, tq5 = 0.f, tq6 = 0.f, tq7 = 0.f;
#pragma unroll 1
    for (int it = 0; it < 4; it++) {
        int v = blockIdx.x * 16 + wave * 4 + it;
        int beg = rp[v], end = rp[v + 1];
        float dv = dinv[v];
        float a0 = 0.f, a1 = 0.f, a2 = 0.f, a3 = 0.f, a4 = 0.f, a5 = 0.f, a6 = 0.f, a7 = 0.f;
        if (p == 0) {  // self-loop term
            uint4 u = Bm4[(size_t)v * 16 + s];
            float2 q0 = bfpair(u.x), q1 = bfpair(u.y), q2 = bfpair(u.z), q3 = bfpair(u.w);
            a0 = q0.x * dv; a1 = q0.y * dv; a2 = q1.x * dv; a3 = q1.y * dv;
            a4 = q2.x * dv; a5 = q2.y * dv; a6 = q3.x * dv; a7 = q3.y * dv;
        }
        int e = beg + p;
        for (; e + 12 < end; e += 16) {  // 4 rows in flight per 16-lane group
            int2 pe0 = cw[e];
            int2 pe1 = cw[e + 4];
            int2 pe2 = cw[e + 8];
            int2 pe3 = cw[e + 12];
            uint4 u0 = Bm4[(size_t)pe0.x * 16 + s];
            uint4 u1 = Bm4[(size_t)pe1.x * 16 + s];
            uint4 u2 = Bm4[(size_t)pe2.x * 16 + s];
            uint4 u3 = Bm4[(size_t)pe3.x * 16 + s];
            float w0 = __int_as_float(pe0.y);
            float w1 = __int_as_float(pe1.y);
            float w2 = __int_as_float(pe2.y);
            float w3 = __int_as_float(pe3.y);
            {
                float2 x0 = bfpair(u0.x), x1 = bfpair(u0.y), x2 = bfpair(u0.z), x3 = bfpair(u0.w);
                a0 += x0.x * w0; a1 += x0.y * w0; a2 += x1.x * w0; a3 += x1.y * w0;
                a4 += x2.x * w0; a5 += x2.y * w0; a6 += x3.x * w0; a7 += x3.y * w0;
            }
            {
                float2 x0 = bfpair(u1.x), x1 = bfpair(u1.y), x2 = bfpair(u1.z), x3 = bfpair(u1.w);
                a0 += x0.x * w1; a1 += x0.y * w1; a2 += x1.x * w1; a3 += x1.y * w1;
                a4 += x2.x * w1; a5 += x2.y * w1; a6 += x3.x * w1; a7 += x3.y * w1;
            }
            {
                float2 x0 = bfpair(u2.x), x1 = bfpair(u2.y), x2 = bfpair(u2.z), x3 = bfpair(u2.w);
                a0 += x0.x * w2; a1 += x0.y * w2; a2 += x1.x * w2; a3 += x1.y * w2;
                a4 += x2.x * w2; a5 += x2.y * w2; a6 += x3.x * w2; a7 += x3.y * w2;
            }
            {
                float2 x0 = bfpair(u3.x), x1 = bfpair(u3.y), x2 = bfpair(u3.z), x3 = bfpair(u3.w);
                a0 += x0.x * w3; a1 += x0.y * w3; a2 += x1.x * w3; a3 += x1.y * w3;
                a4 += x2.x * w3; a5 += x2.y * w3; a6 += x3.x * w3; a7 += x3.y * w3;
            }
        }
        for (; e + 4 < end; e += 8) {
            int2 pe0 = cw[e];
            int2 pe1 = cw[e + 4];
            uint4 u0 = Bm4[(size_t)pe0.x * 16 + s];
            uint4 u1 = Bm4[(size_t)pe1.x * 16 + s];
            float w0 = __int_as_float(pe0.y);
            float w1 = __int_as_float(pe1.y);
            float2 x0 = bfpair(u0.x), x1 = bfpair(u0.y), x2 = bfpair(u0.z), x3 = bfpair(u0.w);
            float2 y0 = bfpair(u1.x), y1 = bfpair(u1.y), y2 = bfpair(u1.z), y3 = bfpair(u1.w);
            a0 += x0.x * w0 + y0.x * w1;
            a1 += x0.y * w0 + y0.y * w1;
            a2 += x1.x * w0 + y1.x * w1;
            a3 += x1.y * w0 + y1.y * w1;
            a4 += x2.x * w0 + y2.x * w1;
            a5 += x2.y * w0 + y2.y * w1;
            a6 += x3.x * w0 + y3.x * w1;
            a7 += x3.y * w0 + y3.y * w1;
        }
        if (e < end) {
            int2 pe = cw[e];
            uint4 u = Bm4[(size_t)pe.x * 16 + s];
            float w = __int_as_float(pe.y);
            float2 x0 = bfpair(u.x), x1 = bfpair(u.y), x2 = bfpair(u.z), x3 = bfpair(u.w);
            a0 += x0.x * w; a1 += x0.y * w; a2 += x1.x * w; a3 += x1.y * w;
            a4 += x2.x * w; a5 += x2.y * w; a6 += x3.x * w; a7 += x3.y * w;
        }
        // combine the four 16-lane groups
        a0 += __shfl_xor(a0, 16); a1 += __shfl_xor(a1, 16);
        a2 += __shfl_xor(a2, 16); a3 += __shfl_xor(a3, 16);
        a4 += __shfl_xor(a4, 16); a5 += __shfl_xor(a5, 16);
        a6 += __shfl_xor(a6, 16); a7 += __shfl_xor(a7, 16);
        a0 += __shfl_xor(a0, 32); a1 += __shfl_xor(a1, 32);
        a2 += __shfl_xor(a2, 32); a3 += __shfl_xor(a3, 32);
        a4 += __shfl_xor(a4, 32); a5 += __shfl_xor(a5, 32);
        a6 += __shfl_xor(a6, 32); a7 += __shfl_xor(a7, 32);
        if (p == 0) {
            float r0 = a0 * dv + bg[f + 0];
            float r1 = a1 * dv + bg[f + 1];
            float r2 = a2 * dv + bg[f + 2];
            float r3 = a3 * dv + bg[f + 3];
            float r4 = a4 * dv + bg[f + 4];
            float r5 = a5 * dv + bg[f + 5];
            float r6 = a6 * dv + bg[f + 6];
            float r7 = a7 * dv + bg[f + 7];
            unsigned short b0 = f2bf(r0), b1 = f2bf(r1), b2 = f2bf(r2), b3 = f2bf(r3);
            unsigned short b4 = f2bf(r4), b5 = f2bf(r5), b6 = f2bf(r6), b7 = f2bf(r7);
            uint4 o;
            o.x = (unsigned)b0 | ((unsigned)b1 << 16);
            o.y = (unsigned)b2 | ((unsigned)b3 << 16);
            o.z = (unsigned)b4 | ((unsigned)b5 << 16);
            o.w = (unsigned)b6 | ((unsigned)b7 << 16);
            *(uint4*)&Aout[(size_t)v * HID + f] = o;
            // BN stats on the bf16-rounded values (what the next GEMM sees)
            float v0 = bf2f(b0), v1 = bf2f(b1), v2 = bf2f(b2), v3 = bf2f(b3);
            float v4 = bf2f(b4), v5 = bf2f(b5), v6 = bf2f(b6), v7 = bf2f(b7);
            ts0 += v0; ts1 += v1; ts2 += v2; ts3 += v3;
            ts4 += v4; ts5 += v5; ts6 += v6; ts7 += v7;
            tq0 += v0 * v0; tq1 += v1 * v1; tq2 += v2 * v2; tq3 += v3 * v3;
            tq4 += v4 * v4; tq5 += v5 * v5; tq6 += v6 * v6; tq7 += v7 * v7;
        }
    }
    if (p == 0) {
        float* lsw = &ls[wave * HID + f];
        float* lqw = &lq[wave * HID + f];
        lsw[0] = ts0; lsw[1] = ts1; lsw[2] = ts2; lsw[3] = ts3;
        lsw[4] = ts4; lsw[5] = ts5; lsw[6] = ts6; lsw[7] = ts7;
        lqw[0] = tq0; lqw[1] = tq1; lqw[2] = tq2; lqw[3] = tq3;
        lqw[4] = tq4; lqw[5] = tq5; lqw[6] = tq6; lqw[7] = tq7;
    }
    __syncthreads();
    int tt = threadIdx.x;
    if (tt < HID) {
        float ssum = ls[tt] + ls[HID + tt] + ls[2 * HID + tt] + ls[3 * HID + tt];
        float ssq = lq[tt] + lq[HID + tt] + lq[2 * HID + tt] + lq[3 * HID + tt];
        int slot = blockIdx.x & (BSLOT - 1);
        atomicAdd(&psum[slot * HID + tt], ssum);
        atomicAdd(&psq[slot * HID + tt], ssq);
    }
}

// ---------------- segmented pooling, chunked; derives layer-3 BN in-kernel ----------------

__global__ __launch_bounds__(128) void k_pool(const unsigned short* __restrict__ A,
                                              const float* __restrict__ psum,
                                              const float* __restrict__ psq,
                                              const float* __restrict__ gamma,
                                              const float* __restrict__ beta,
                                              const int* __restrict__ gstart,
                                              float* __restrict__ poolPart) {
    int g = blockIdx.x;
    int c = blockIdx.y;
    int f = threadIdx.x;
    float s = 0.f, s2 = 0.f;
#pragma unroll 8
    for (int b = 0; b < BSLOT; b++) {
        s += psum[b * HID + f];
        s2 += psq[b * HID + f];
    }
    const float invN = 1.f / (float)N_NODES;
    float mu = s * invN;
    float var = s2 * invN - mu * mu;
    float sc = rsqrtf(var + EPS) * gamma[f];
    float sh = beta[f] - mu * sc;
    int beg = gstart[g], end = gstart[g + 1];
    int len = end - beg;
    int per = (len + POOL_CHUNKS - 1) / POOL_CHUNKS;
    int s0 = beg + c * per;
    int s1 = min(s0 + per, end);
    float sa = 0.f, sb = 0.f, ma = 0.f, mb = 0.f;
    int n = s0;
    for (; n + 1 < s1; n += 2) {
        float v0 = bf2f(A[(size_t)n * HID + f]);
        float v1 = bf2f(A[(size_t)(n + 1) * HID + f]);
        v0 = fmaxf(v0 * sc + sh, 0.f);
        v1 = fmaxf(v1 * sc + sh, 0.f);
        sa += v0; ma = fmaxf(ma, v0);
        sb += v1; mb = fmaxf(mb, v1);
    }
    if (n < s1) {
        float v = fmaxf(bf2f(A[(size_t)n * HID + f]) * sc + sh, 0.f);
        sa += v; ma = fmaxf(ma, v);
    }
    poolPart[((size_t)g * POOL_CHUNKS + c) * 256 + f] = sa + sb;
    poolPart[((size_t)g * POOL_CHUNKS + c) * 256 + 128 + f] = fmaxf(ma, mb);
}

// ---------------- MLP head ----------------

__global__ __launch_bounds__(128) void k_head(const float* __restrict__ poolPart,
                                              const int* __restrict__ gstart,
                                              const float* __restrict__ W1, const float* __restrict__ b1,
                                              const float* __restrict__ W2, const float* __restrict__ b2,
                                              const float* __restrict__ W3, const float* __restrict__ b3,
                                              float* __restrict__ out) {
    __shared__ float pl[2 * HID];
    __shared__ float h1[HID];
    __shared__ float h2[HID / 2];
    int g = blockIdx.x, t = threadIdx.x;
    float cnt = fmaxf((float)(gstart[g + 1] - gstart[g]), 1.f);
    float s = 0.f, mx = 0.f;
#pragma unroll
    for (int c = 0; c < POOL_CHUNKS; c++) {
        const float* p = &poolPart[((size_t)g * POOL_CHUNKS + c) * 256];
        s += p[t];
        mx = fmaxf(mx, p[128 + t]);
    }
    pl[t] = s / cnt;
    pl[HID + t] = mx;
    __syncthreads();
    float acc = b1[t];
    for (int k = 0; k < 2 * HID; k++) acc += pl[k] * W1[k * HID + t];
    h1[t] = fmaxf(acc, 0.f);
    __syncthreads();
    if (t < HID / 2) {
        float a2 = b2[t];
        for (int k = 0; k < HID; k++) a2 += h1[k] * W2[k * (HID / 2) + t];
        h2[t] = fmaxf(a2, 0.f);
    }
    __syncthreads();
    if (t < NCLS) {
        float a3 = b3[t];
        for (int k = 0; k < HID / 2; k++) a3 += h2[k] * W3[k * NCLS + t];
        out[g * NCLS + t] = a3;
    }
}

extern "C" void kernel_launch(void* const* d_in, const int* in_sizes, int n_in,
                              void* d_out, int out_size, void* d_ws, size_t ws_size,
                              hipStream_t stream) {
    const float* x     = (const float*)d_in[0];
    const int*   ei    = (const int*)d_in[1];
    const int*   batch = (const int*)d_in[2];
    const float* Wp    = (const float*)d_in[3];
    const float* bp    = (const float*)d_in[4];
    const float* Wg    = (const float*)d_in[5];
    const float* bg    = (const float*)d_in[6];
    const float* gamma = (const float*)d_in[7];
    const float* beta  = (const float*)d_in[8];
    const float* W1    = (const float*)d_in[9];
    const float* b1    = (const float*)d_in[10];
    const float* W2    = (const float*)d_in[11];
    const float* b2    = (const float*)d_in[12];
    const float* W3    = (const float*)d_in[13];
    const float* b3    = (const float*)d_in[14];
    const int* src = ei;
    const int* dst = ei + N_EDGES;
    float* out = (float*)d_out;

    char* base = (char*)d_ws;
    size_t off = 0;
    auto alloc = [&](size_t bytes) -> void* {
        void* p = base + off;
        off += (bytes + 255) & ~(size_t)255;
        return p;
    };
    // zeroed region (one memset)
    int*   counts = (int*)alloc((size_t)N_NODES * 4);
    int*   cursor = (int*)alloc((size_t)N_NODES * 4);
    float* psum   = (float*)alloc((size_t)NLAYERS * BSLOT * HID * 4);
    float* psq    = (float*)alloc((size_t)NLAYERS * BSLOT * HID * 4);
    size_t zeroBytes = off;
    // non-zeroed scratch
    int*   rp      = (int*)alloc((size_t)(N_NODES + 1) * 4);
    int*   bsum    = (int*)alloc(128 * 4);
    int2*  cw      = (int2*)alloc((size_t)N_EDGES * 8);
    float* dinv    = (float*)alloc((size_t)N_NODES * 4);
    int*   gstart  = (int*)alloc((size_t)(N_GRAPHS + 1) * 4);
    float* poolPart= (float*)alloc((size_t)N_GRAPHS * POOL_CHUNKS * 256 * 4);
    unsigned short* WtG = (unsigned short*)alloc((size_t)NLAYERS * HID * HID * 2);
    unsigned short* A = (unsigned short*)alloc((size_t)N_NODES * HID * 2);
    unsigned short* B = (unsigned short*)alloc((size_t)N_NODES * HID * 2);
    (void)ws_size; (void)in_sizes; (void)n_in; (void)out_size;

    hipMemsetAsync(d_ws, 0, zeroBytes, stream);

    k_count<<<(N_EDGES + 255) / 256, 256, 0, stream>>>(dst, counts);
    k_scan1<<<SCAN_BLK, 512, 0, stream>>>(counts, rp, bsum);
    k_scan2g<<<2, 128, 0, stream>>>(bsum, batch, gstart);
    k_scan3d<<<SCAN_BLK, 512, 0, stream>>>(rp, bsum, counts, dinv);
    k_fillw<<<FILL_BLK + (NLAYERS * HID * HID) / 256, 256, 0, stream>>>(
        src, dst, rp, cursor, cw, dinv, Wg, WtG);

    for (int i = 0; i < NLAYERS; i++) {
        int pl = (i == 0) ? 0 : (i - 1);
        k_gemmM<<<768, 256, 0, stream>>>(A, x, Wp, bp, WtG + (size_t)i * HID * HID, B,
                                         psum + (size_t)pl * BSLOT * HID,
                                         psq + (size_t)pl * BSLOT * HID,
                                         gamma + pl * HID, beta + pl * HID,
                                         (i == 0) ? 1 : 0);
        k_gather<<<N_NODES / 16, 256, 0, stream>>>((const uint4*)B, rp, cw, dinv,
                                                   bg + i * HID, A,
                                                   psum + (size_t)i * BSLOT * HID,
                                                   psq + (size_t)i * BSLOT * HID);
    }
    dim3 pg(N_GRAPHS, POOL_CHUNKS);
    k_pool<<<pg, 128, 0, stream>>>(A, psum + (size_t)3 * BSLOT * HID,
                                   psq + (size_t)3 * BSLOT * HID,
                                   gamma + 3 * HID, beta + 3 * HID, gstart, poolPart);
    k_head<<<N_GRAPHS, 128, 0, stream>>>(poolPart, gstart, W1, b1, W2, b2, W3, b3, out);
}

// Round 12
// 390.014 us; speedup vs baseline: 2.6914x; 1.0836x over previous
//
#include <hip/hip_runtime.h>
#include <hip/hip_bf16.h>

#define N_NODES 50000
#define N_EDGES 600000
#define N_GRAPHS 64
#define HID 128
#define NLAYERS 4
#define IN_DIM 5
#define NCLS 5
#define EPS 1e-5f
#define SCAN_BLK ((N_NODES + 511) / 512)
#define FILL_BLK ((N_EDGES + 255) / 256)
#define POOL_CHUNKS 16
#define BSLOT 64  // BN-stat atomic slots (per layer)
#define WS 136    // bf16 LDS row stride (MFMA kernel)

typedef __attribute__((ext_vector_type(8))) short s16x8;
typedef __attribute__((ext_vector_type(4))) float f32x4;

// bf16 helpers (RNE)
__device__ __forceinline__ unsigned short f2bf(float x) {
    unsigned u = __float_as_uint(x);
    unsigned r = (u + 0x7fffu + ((u >> 16) & 1u)) >> 16;
    return (unsigned short)r;
}
__device__ __forceinline__ float2 bfpair(unsigned u) {
    float2 r;
    r.x = __uint_as_float(u << 16);
    r.y = __uint_as_float(u & 0xffff0000u);
    return r;
}
__device__ __forceinline__ float bf2f(unsigned short s) {
    return __uint_as_float(((unsigned)s) << 16);
}

// ---------------- CSR build ----------------

__global__ void k_count(const int* __restrict__ dst, int* __restrict__ cnt) {
    int i = blockIdx.x * blockDim.x + threadIdx.x;
    if (i < N_EDGES) atomicAdd(&cnt[dst[i]], 1);
}

__global__ void k_scan1(const int* __restrict__ cnt, int* __restrict__ rp, int* __restrict__ bsum) {
    __shared__ int s[512];
    int t = threadIdx.x;
    int i = blockIdx.x * 512 + t;
    int v = (i < N_NODES) ? cnt[i] : 0;
    s[t] = v;
    __syncthreads();
    for (int off = 1; off < 512; off <<= 1) {
        int x = (t >= off) ? s[t - off] : 0;
        __syncthreads();
        s[t] += x;
        __syncthreads();
    }
    if (i < N_NODES) rp[i + 1] = s[t];
    if (t == 511) bsum[blockIdx.x] = s[511];
}

__global__ void k_scan2g(int* __restrict__ bsum, const int* __restrict__ batch,
                         int* __restrict__ gstart) {
    if (blockIdx.x == 0) {
        __shared__ int s[128];
        int t = threadIdx.x;
        int v = (t < SCAN_BLK) ? bsum[t] : 0;
        s[t] = v;
        __syncthreads();
        for (int off = 1; off < 128; off <<= 1) {
            int x = (t >= off) ? s[t - off] : 0;
            __syncthreads();
            s[t] += x;
            __syncthreads();
        }
        if (t < SCAN_BLK) bsum[t] = s[t] - v;
    } else {
        int t = threadIdx.x;
        if (t <= N_GRAPHS) {
            int lo = 0, hi = N_NODES;
            while (lo < hi) {
                int mid = (lo + hi) >> 1;
                if (batch[mid] < t) lo = mid + 1; else hi = mid;
            }
            gstart[t] = lo;
        }
    }
}

__global__ void k_scan3d(int* __restrict__ rp, const int* __restrict__ bsum,
                         const int* __restrict__ cnt, float* __restrict__ dinv) {
    int i = blockIdx.x * 512 + threadIdx.x;
    if (i < N_NODES) {
        rp[i + 1] += bsum[blockIdx.x];
        dinv[i] = rsqrtf((float)(cnt[i] + 1));
    }
    if (i == 0) rp[0] = 0;
}

// fill packed (col, w) pairs; trailing blocks do the W transpose+bf16 convert
__global__ void k_fillw(const int* __restrict__ src, const int* __restrict__ dst,
                        const int* __restrict__ rp, int* __restrict__ cursor,
                        int2* __restrict__ cw, const float* __restrict__ dinv,
                        const float* __restrict__ Wg, unsigned short* __restrict__ WtG) {
    int b = blockIdx.x;
    if (b < FILL_BLK) {
        int e = b * 256 + threadIdx.x;
        if (e < N_EDGES) {
            int d = dst[e];
            int pos = atomicAdd(&cursor[d], 1);
            int s = src[e];
            int2 p;
            p.x = s;
            p.y = __float_as_int(dinv[s]);
            cw[rp[d] + pos] = p;
        }
    } else {
        int idx = (b - FILL_BLK) * 256 + threadIdx.x;  // < NLAYERS*HID*HID
        int l = idx >> 14;
        int r = idx & 16383;
        int n = r >> 7, k = r & 127;
        WtG[idx] = f2bf(Wg[l * HID * HID + k * HID + n]);
    }
}

// ---------------- GEMM (MFMA): Bm(bf16) = act(in) @ W ----------------
// layer0: in = x @ Wp + bp (computed per tile). Else: in = relu(A*sc+sh),
// sc/sh derived in-kernel from the previous gather's psum/psq slots.
// W comes pre-transposed+bf16 (WtG[n][k]) -> coalesced uint4 + ds_write_b128.

__global__ __launch_bounds__(256) void k_gemmM(const unsigned short* __restrict__ Abf,
                                               const float* __restrict__ x,
                                               const float* __restrict__ Wp,
                                               const float* __restrict__ bp,
                                               const unsigned short* __restrict__ WtG,
                                               unsigned short* __restrict__ Bm,
                                               const float* __restrict__ psum,
                                               const float* __restrict__ psq,
                                               const float* __restrict__ gamma,
                                               const float* __restrict__ beta,
                                               int layer0) {
    __shared__ unsigned short Wt[HID * WS];
    __shared__ unsigned short Al[64 * WS];
    __shared__ float scl[HID], shf[HID];
    __shared__ float Wpl[IN_DIM * HID];
    __shared__ float bpl[HID];
    __shared__ float xl[64 * IN_DIM];
    int t = threadIdx.x;
    {
        const uint4* Wg4 = (const uint4*)WtG;
        for (int idx = t; idx < HID * 16; idx += 256) {
            int n = idx >> 4, c = idx & 15;
            *(uint4*)&Wt[n * WS + c * 8] = Wg4[idx];
        }
    }
    if (layer0) {
        for (int idx = t; idx < IN_DIM * HID; idx += 256) Wpl[idx] = Wp[idx];
        if (t < HID) bpl[t] = bp[t];
    } else if (t < HID) {
        float s = 0.f, s2 = 0.f;
#pragma unroll 8
        for (int b = 0; b < BSLOT; b++) {
            s += psum[b * HID + t];
            s2 += psq[b * HID + t];
        }
        const float invN = 1.f / (float)N_NODES;
        float mu = s * invN;
        float var = s2 * invN - mu * mu;
        float rs = rsqrtf(var + EPS) * gamma[t];
        scl[t] = rs;
        shf[t] = beta[t] - mu * rs;
    }
    int lane = t & 63, wv = t >> 6;
    int rbase = (wv & 1) * 32;
    int cbase = (wv >> 1) * 64;
    int mr = lane & 15, q = lane >> 4;
    const int numTiles = (N_NODES + 63) / 64;
    for (int tile = blockIdx.x; tile < numTiles; tile += gridDim.x) {
        int n0 = tile * 64;
        __syncthreads();  // orders scl/Wt writes (1st iter) + Al reuse safety
        if (layer0) {
            for (int idx = t; idx < 64 * IN_DIM; idx += 256) {
                int g = n0 * IN_DIM + idx;
                xl[idx] = (g < N_NODES * IN_DIM) ? x[g] : 0.f;
            }
            __syncthreads();
            for (int idx = t; idx < 64 * HID; idx += 256) {
                int n = idx >> 7, k = idx & 127;
                float acc = bpl[k];
#pragma unroll
                for (int j = 0; j < IN_DIM; j++) acc += xl[n * IN_DIM + j] * Wpl[j * HID + k];
                Al[n * WS + k] = f2bf(acc);
            }
        } else {
            const uint2* Ag = (const uint2*)(Abf + (size_t)n0 * HID);
            int limRow = min(64, N_NODES - n0);
            for (int idx = t; idx < 64 * 32; idx += 256) {
                int row = idx >> 5, c4 = idx & 31;
                uint2 u = (row < limRow) ? Ag[row * 32 + c4] : make_uint2(0u, 0u);
                float2 ab = bfpair(u.x);
                float2 cd = bfpair(u.y);
                int kf = c4 * 4;
                float4 sc = *(const float4*)&scl[kf];
                float4 sh = *(const float4*)&shf[kf];
                float v0 = fmaxf(ab.x * sc.x + sh.x, 0.f);
                float v1 = fmaxf(ab.y * sc.y + sh.y, 0.f);
                float v2 = fmaxf(cd.x * sc.z + sh.z, 0.f);
                float v3 = fmaxf(cd.y * sc.w + sh.w, 0.f);
                unsigned lo = (unsigned)f2bf(v0) | ((unsigned)f2bf(v1) << 16);
                unsigned hi = (unsigned)f2bf(v2) | ((unsigned)f2bf(v3) << 16);
                *(uint2*)&Al[row * WS + kf] = make_uint2(lo, hi);
            }
        }
        __syncthreads();
        f32x4 acc[2][4];
#pragma unroll
        for (int rt = 0; rt < 2; rt++)
#pragma unroll
            for (int ct = 0; ct < 4; ct++) acc[rt][ct] = (f32x4){0.f, 0.f, 0.f, 0.f};
#pragma unroll
        for (int kk = 0; kk < HID; kk += 32) {
            s16x8 a0 = *(const s16x8*)&Al[(rbase + mr) * WS + kk + q * 8];
            s16x8 a1 = *(const s16x8*)&Al[(rbase + 16 + mr) * WS + kk + q * 8];
#pragma unroll
            for (int ct = 0; ct < 4; ct++) {
                s16x8 b = *(const s16x8*)&Wt[(cbase + ct * 16 + mr) * WS + kk + q * 8];
                acc[0][ct] = __builtin_amdgcn_mfma_f32_16x16x32_bf16(a0, b, acc[0][ct], 0, 0, 0);
                acc[1][ct] = __builtin_amdgcn_mfma_f32_16x16x32_bf16(a1, b, acc[1][ct], 0, 0, 0);
            }
        }
#pragma unroll
        for (int rt = 0; rt < 2; rt++)
#pragma unroll
            for (int ct = 0; ct < 4; ct++)
#pragma unroll
                for (int r = 0; r < 4; r++) {
                    int node = n0 + rbase + rt * 16 + q * 4 + r;
                    if (node < N_NODES) {
                        int f = cbase + ct * 16 + mr;
                        Bm[(size_t)node * HID + f] = f2bf(acc[rt][ct][r]);
                    }
                }
    }
}

// ---------------- CSR gather + fused BN partial stats ----------------
// 16 nodes per block: 4 waves x 4 serial nodes. Within a node, four 16-lane
// groups each fetch a DIFFERENT edge's 256B row (uint4/lane), unroll x2 ->
// 8 rows in flight per wave (empirical optimum: x4 unroll cost occupancy and
// regressed R11; 1 row/wave-instr regressed R6). BN stats in registers across
// the 4 nodes; one LDS reduce + 256-atomic tail per block.

__global__ __launch_bounds__(256) void k_gather(const uint4* __restrict__ Bm4,
                                                const int* __restrict__ rp,
                                                const int2* __restrict__ cw,
                                                const float* __restrict__ dinv,
                                                const float* __restrict__ bg,
                                                unsigned short* __restrict__ Aout,
                                                float* __restrict__ psum,
                                                float* __restrict__ psq) {
    __shared__ float ls[4 * HID], lq[4 * HID];
    int wave = threadIdx.x >> 6;
    int lane = threadIdx.x & 63;
    int s = lane & 15;   // 16B feature chunk: features s*8 .. s*8+7
    int p = lane >> 4;   // edge slot 0..3
    int f = s * 8;
    float ts0 = 0.f, ts1 = 0.f, ts2 = 0.f, ts3 = 0.f, ts4 = 0.f, ts5 = 0.f, ts6 = 0.f, ts7 = 0.f;
    float tq0 = 0.f, tq1 = 0.f, tq2 = 0.f, tq3 = 0.f, tq4 = 0.f, tq5 = 0.f, tq6 = 0.f, tq7 = 0.f;
#pragma unroll 1
    for (int it = 0; it < 4; it++) {
        int v = blockIdx.x * 16 + wave * 4 + it;
        int beg = rp[v], end = rp[v + 1];
        float dv = dinv[v];
        float a0 = 0.f, a1 = 0.f, a2 = 0.f, a3 = 0.f, a4 = 0.f, a5 = 0.f, a6 = 0.f, a7 = 0.f;
        if (p == 0) {  // self-loop term
            uint4 u = Bm4[(size_t)v * 16 + s];
            float2 q0 = bfpair(u.x), q1 = bfpair(u.y), q2 = bfpair(u.z), q3 = bfpair(u.w);
            a0 = q0.x * dv; a1 = q0.y * dv; a2 = q1.x * dv; a3 = q1.y * dv;
            a4 = q2.x * dv; a5 = q2.y * dv; a6 = q3.x * dv; a7 = q3.y * dv;
        }
        int e = beg + p;
        for (; e + 4 < end; e += 8) {
            int2 pe0 = cw[e];
            int2 pe1 = cw[e + 4];
            uint4 u0 = Bm4[(size_t)pe0.x * 16 + s];
            uint4 u1 = Bm4[(size_t)pe1.x * 16 + s];
            float w0 = __int_as_float(pe0.y);
            float w1 = __int_as_float(pe1.y);
            float2 x0 = bfpair(u0.x), x1 = bfpair(u0.y), x2 = bfpair(u0.z), x3 = bfpair(u0.w);
            float2 y0 = bfpair(u1.x), y1 = bfpair(u1.y), y2 = bfpair(u1.z), y3 = bfpair(u1.w);
            a0 += x0.x * w0 + y0.x * w1;
            a1 += x0.y * w0 + y0.y * w1;
            a2 += x1.x * w0 + y1.x * w1;
            a3 += x1.y * w0 + y1.y * w1;
            a4 += x2.x * w0 + y2.x * w1;
            a5 += x2.y * w0 + y2.y * w1;
            a6 += x3.x * w0 + y3.x * w1;
            a7 += x3.y * w0 + y3.y * w1;
        }
        if (e < end) {
            int2 pe = cw[e];
            uint4 u = Bm4[(size_t)pe.x * 16 + s];
            float w = __int_as_float(pe.y);
            float2 x0 = bfpair(u.x), x1 = bfpair(u.y), x2 = bfpair(u.z), x3 = bfpair(u.w);
            a0 += x0.x * w; a1 += x0.y * w; a2 += x1.x * w; a3 += x1.y * w;
            a4 += x2.x * w; a5 += x2.y * w; a6 += x3.x * w; a7 += x3.y * w;
        }
        // combine the four 16-lane groups
        a0 += __shfl_xor(a0, 16); a1 += __shfl_xor(a1, 16);
        a2 += __shfl_xor(a2, 16); a3 += __shfl_xor(a3, 16);
        a4 += __shfl_xor(a4, 16); a5 += __shfl_xor(a5, 16);
        a6 += __shfl_xor(a6, 16); a7 += __shfl_xor(a7, 16);
        a0 += __shfl_xor(a0, 32); a1 += __shfl_xor(a1, 32);
        a2 += __shfl_xor(a2, 32); a3 += __shfl_xor(a3, 32);
        a4 += __shfl_xor(a4, 32); a5 += __shfl_xor(a5, 32);
        a6 += __shfl_xor(a6, 32); a7 += __shfl_xor(a7, 32);
        if (p == 0) {
            float r0 = a0 * dv + bg[f + 0];
            float r1 = a1 * dv + bg[f + 1];
            float r2 = a2 * dv + bg[f + 2];
            float r3 = a3 * dv + bg[f + 3];
            float r4 = a4 * dv + bg[f + 4];
            float r5 = a5 * dv + bg[f + 5];
            float r6 = a6 * dv + bg[f + 6];
            float r7 = a7 * dv + bg[f + 7];
            unsigned short b0 = f2bf(r0), b1 = f2bf(r1), b2 = f2bf(r2), b3 = f2bf(r3);
            unsigned short b4 = f2bf(r4), b5 = f2bf(r5), b6 = f2bf(r6), b7 = f2bf(r7);
            uint4 o;
            o.x = (unsigned)b0 | ((unsigned)b1 << 16);
            o.y = (unsigned)b2 | ((unsigned)b3 << 16);
            o.z = (unsigned)b4 | ((unsigned)b5 << 16);
            o.w = (unsigned)b6 | ((unsigned)b7 << 16);
            *(uint4*)&Aout[(size_t)v * HID + f] = o;
            // BN stats on the bf16-rounded values (what the next GEMM sees)
            float v0 = bf2f(b0), v1 = bf2f(b1), v2 = bf2f(b2), v3 = bf2f(b3);
            float v4 = bf2f(b4), v5 = bf2f(b5), v6 = bf2f(b6), v7 = bf2f(b7);
            ts0 += v0; ts1 += v1; ts2 += v2; ts3 += v3;
            ts4 += v4; ts5 += v5; ts6 += v6; ts7 += v7;
            tq0 += v0 * v0; tq1 += v1 * v1; tq2 += v2 * v2; tq3 += v3 * v3;
            tq4 += v4 * v4; tq5 += v5 * v5; tq6 += v6 * v6; tq7 += v7 * v7;
        }
    }
    if (p == 0) {
        float* lsw = &ls[wave * HID + f];
        float* lqw = &lq[wave * HID + f];
        lsw[0] = ts0; lsw[1] = ts1; lsw[2] = ts2; lsw[3] = ts3;
        lsw[4] = ts4; lsw[5] = ts5; lsw[6] = ts6; lsw[7] = ts7;
        lqw[0] = tq0; lqw[1] = tq1; lqw[2] = tq2; lqw[3] = tq3;
        lqw[4] = tq4; lqw[5] = tq5; lqw[6] = tq6; lqw[7] = tq7;
    }
    __syncthreads();
    int tt = threadIdx.x;
    if (tt < HID) {
        float ssum = ls[tt] + ls[HID + tt] + ls[2 * HID + tt] + ls[3 * HID + tt];
        float ssq = lq[tt] + lq[HID + tt] + lq[2 * HID + tt] + lq[3 * HID + tt];
        int slot = blockIdx.x & (BSLOT - 1);
        atomicAdd(&psum[slot * HID + tt], ssum);
        atomicAdd(&psq[slot * HID + tt], ssq);
    }
}

// ---------------- segmented pooling, chunked; derives layer-3 BN in-kernel ----------------

__global__ __launch_bounds__(128) void k_pool(const unsigned short* __restrict__ A,
                                              const float* __restrict__ psum,
                                              const float* __restrict__ psq,
                                              const float* __restrict__ gamma,
                                              const float* __restrict__ beta,
                                              const int* __restrict__ gstart,
                                              float* __restrict__ poolPart) {
    int g = blockIdx.x;
    int c = blockIdx.y;
    int f = threadIdx.x;
    float s = 0.f, s2 = 0.f;
#pragma unroll 8
    for (int b = 0; b < BSLOT; b++) {
        s += psum[b * HID + f];
        s2 += psq[b * HID + f];
    }
    const float invN = 1.f / (float)N_NODES;
    float mu = s * invN;
    float var = s2 * invN - mu * mu;
    float sc = rsqrtf(var + EPS) * gamma[f];
    float sh = beta[f] - mu * sc;
    int beg = gstart[g], end = gstart[g + 1];
    int len = end - beg;
    int per = (len + POOL_CHUNKS - 1) / POOL_CHUNKS;
    int s0 = beg + c * per;
    int s1 = min(s0 + per, end);
    float sa = 0.f, sb = 0.f, ma = 0.f, mb = 0.f;
    int n = s0;
    for (; n + 1 < s1; n += 2) {
        float v0 = bf2f(A[(size_t)n * HID + f]);
        float v1 = bf2f(A[(size_t)(n + 1) * HID + f]);
        v0 = fmaxf(v0 * sc + sh, 0.f);
        v1 = fmaxf(v1 * sc + sh, 0.f);
        sa += v0; ma = fmaxf(ma, v0);
        sb += v1; mb = fmaxf(mb, v1);
    }
    if (n < s1) {
        float v = fmaxf(bf2f(A[(size_t)n * HID + f]) * sc + sh, 0.f);
        sa += v; ma = fmaxf(ma, v);
    }
    poolPart[((size_t)g * POOL_CHUNKS + c) * 256 + f] = sa + sb;
    poolPart[((size_t)g * POOL_CHUNKS + c) * 256 + 128 + f] = fmaxf(ma, mb);
}

// ---------------- MLP head ----------------

__global__ __launch_bounds__(128) void k_head(const float* __restrict__ poolPart,
                                              const int* __restrict__ gstart,
                                              const float* __restrict__ W1, const float* __restrict__ b1,
                                              const float* __restrict__ W2, const float* __restrict__ b2,
                                              const float* __restrict__ W3, const float* __restrict__ b3,
                                              float* __restrict__ out) {
    __shared__ float pl[2 * HID];
    __shared__ float h1[HID];
    __shared__ float h2[HID / 2];
    int g = blockIdx.x, t = threadIdx.x;
    float cnt = fmaxf((float)(gstart[g + 1] - gstart[g]), 1.f);
    float s = 0.f, mx = 0.f;
#pragma unroll
    for (int c = 0; c < POOL_CHUNKS; c++) {
        const float* p = &poolPart[((size_t)g * POOL_CHUNKS + c) * 256];
        s += p[t];
        mx = fmaxf(mx, p[128 + t]);
    }
    pl[t] = s / cnt;
    pl[HID + t] = mx;
    __syncthreads();
    float acc = b1[t];
    for (int k = 0; k < 2 * HID; k++) acc += pl[k] * W1[k * HID + t];
    h1[t] = fmaxf(acc, 0.f);
    __syncthreads();
    if (t < HID / 2) {
        float a2 = b2[t];
        for (int k = 0; k < HID; k++) a2 += h1[k] * W2[k * (HID / 2) + t];
        h2[t] = fmaxf(a2, 0.f);
    }
    __syncthreads();
    if (t < NCLS) {
        float a3 = b3[t];
        for (int k = 0; k < HID / 2; k++) a3 += h2[k] * W3[k * NCLS + t];
        out[g * NCLS + t] = a3;
    }
}

extern "C" void kernel_launch(void* const* d_in, const int* in_sizes, int n_in,
                              void* d_out, int out_size, void* d_ws, size_t ws_size,
                              hipStream_t stream) {
    const float* x     = (const float*)d_in[0];
    const int*   ei    = (const int*)d_in[1];
    const int*   batch = (const int*)d_in[2];
    const float* Wp    = (const float*)d_in[3];
    const float* bp    = (const float*)d_in[4];
    const float* Wg    = (const float*)d_in[5];
    const float* bg    = (const float*)d_in[6];
    const float* gamma = (const float*)d_in[7];
    const float* beta  = (const float*)d_in[8];
    const float* W1    = (const float*)d_in[9];
    const float* b1    = (const float*)d_in[10];
    const float* W2    = (const float*)d_in[11];
    const float* b2    = (const float*)d_in[12];
    const float* W3    = (const float*)d_in[13];
    const float* b3    = (const float*)d_in[14];
    const int* src = ei;
    const int* dst = ei + N_EDGES;
    float* out = (float*)d_out;

    char* base = (char*)d_ws;
    size_t off = 0;
    auto alloc = [&](size_t bytes) -> void* {
        void* p = base + off;
        off += (bytes + 255) & ~(size_t)255;
        return p;
    };
    // zeroed region (one memset)
    int*   counts = (int*)alloc((size_t)N_NODES * 4);
    int*   cursor = (int*)alloc((size_t)N_NODES * 4);
    float* psum   = (float*)alloc((size_t)NLAYERS * BSLOT * HID * 4);
    float* psq    = (float*)alloc((size_t)NLAYERS * BSLOT * HID * 4);
    size_t zeroBytes = off;
    // non-zeroed scratch
    int*   rp      = (int*)alloc((size_t)(N_NODES + 1) * 4);
    int*   bsum    = (int*)alloc(128 * 4);
    int2*  cw      = (int2*)alloc((size_t)N_EDGES * 8);
    float* dinv    = (float*)alloc((size_t)N_NODES * 4);
    int*   gstart  = (int*)alloc((size_t)(N_GRAPHS + 1) * 4);
    float* poolPart= (float*)alloc((size_t)N_GRAPHS * POOL_CHUNKS * 256 * 4);
    unsigned short* WtG = (unsigned short*)alloc((size_t)NLAYERS * HID * HID * 2);
    unsigned short* A = (unsigned short*)alloc((size_t)N_NODES * HID * 2);
    unsigned short* B = (unsigned short*)alloc((size_t)N_NODES * HID * 2);
    (void)ws_size; (void)in_sizes; (void)n_in; (void)out_size;

    hipMemsetAsync(d_ws, 0, zeroBytes, stream);

    k_count<<<(N_EDGES + 255) / 256, 256, 0, stream>>>(dst, counts);
    k_scan1<<<SCAN_BLK, 512, 0, stream>>>(counts, rp, bsum);
    k_scan2g<<<2, 128, 0, stream>>>(bsum, batch, gstart);
    k_scan3d<<<SCAN_BLK, 512, 0, stream>>>(rp, bsum, counts, dinv);
    k_fillw<<<FILL_BLK + (NLAYERS * HID * HID) / 256, 256, 0, stream>>>(
        src, dst, rp, cursor, cw, dinv, Wg, WtG);

    for (int i = 0; i < NLAYERS; i++) {
        int pl = (i == 0) ? 0 : (i - 1);
        k_gemmM<<<768, 256, 0, stream>>>(A, x, Wp, bp, WtG + (size_t)i * HID * HID, B,
                                         psum + (size_t)pl * BSLOT * HID,
                                         psq + (size_t)pl * BSLOT * HID,
                                         gamma + pl * HID, beta + pl * HID,
                                         (i == 0) ? 1 : 0);
        k_gather<<<N_NODES / 16, 256, 0, stream>>>((const uint4*)B, rp, cw, dinv,
                                                   bg + i * HID, A,
                                                   psum + (size_t)i * BSLOT * HID,
                                                   psq + (size_t)i * BSLOT * HID);
    }
    dim3 pg(N_GRAPHS, POOL_CHUNKS);
    k_pool<<<pg, 128, 0, stream>>>(A, psum + (size_t)3 * BSLOT * HID,
                                   psq + (size_t)3 * BSLOT * HID,
                                   gamma + 3 * HID, beta + 3 * HID, gstart, poolPart);
    k_head<<<N_GRAPHS, 128, 0, stream>>>(poolPart, gstart, W1, b1, W2, b2, W3, b3, out);
}